// Round 5
// baseline (239.823 us; speedup 1.0000x reference)
//
#include <hip/hip_runtime.h>
#include <hip/hip_bf16.h>
#include <stdint.h>

#define WIDTH 4096
#define NROWS 8192
#define NHEADS 8
#define BW 512
#define CS 128
#define NCHUNK (NROWS/CS)

typedef short bf16x8 __attribute__((ext_vector_type(8)));
typedef float f32x4 __attribute__((ext_vector_type(4)));

__device__ __forceinline__ uint32_t rne_bf16(float f) {
  uint32_t u = __float_as_uint(f);
  return (u + 0x7fffu + ((u >> 16) & 1u)) >> 16;
}
__device__ __forceinline__ uint32_t pack2(float lo, float hi) {
  return rne_bf16(lo) | (rne_bf16(hi) << 16);
}
__device__ __forceinline__ float bf16_to_f32(uint32_t bits) {
  return __uint_as_float(bits << 16);
}

__device__ __forceinline__ void gload_lds16(const void* g, void* l) {
  __builtin_amdgcn_global_load_lds(
      (const __attribute__((address_space(1))) void*)g,
      (__attribute__((address_space(3))) void*)l, 16, 0, 0);
}

// ---- prep: transpose weights f32 [h][i][j] -> bf16 [g*8+h][j][i] ----
__global__ void prep_weights(const float* __restrict__ ig_w,
                             const float* __restrict__ ag_w,
                             uint16_t* __restrict__ wt) {
  __shared__ float tile[32][33];
  int j0 = blockIdx.x * 32;
  int i0 = blockIdx.y * 32;
  int m  = blockIdx.z;  // g*8+h
  const float* src = ((m >> 3) ? ag_w : ig_w) + (size_t)(m & 7) * BW * BW;
  int tx = threadIdx.x & 31, ty = threadIdx.x >> 5;
  #pragma unroll
  for (int k = 0; k < 4; k++) {
    int i = i0 + ty + 8 * k;
    tile[ty + 8 * k][tx] = src[(size_t)i * BW + (j0 + tx)];
  }
  __syncthreads();
  #pragma unroll
  for (int k = 0; k < 4; k++) {
    int j = j0 + ty + 8 * k;
    wt[((size_t)m * BW + j) * BW + (i0 + tx)] = (uint16_t)rne_bf16(tile[tx][ty + 8 * k]);
  }
}

__global__ void prep_misc(const float* __restrict__ a_param, float* __restrict__ cvec) {
  int i = blockIdx.x * 256 + threadIdx.x;
  if (i < WIDTH) {
    float x = a_param[i];
    float sp = (x > 15.f) ? x : log1pf(expf(x));
    cvec[i] = 8.f * sp;
  }
}

// ---- GEMM: dual-gate bf16 MFMA, tile 256x128, BK=64, 512 thr, dbuf LDS,
//      f32 X staged in-kernel (reg->bf16->LDS), rotated K order so output
//      X-slices end resident in LDS for the epilogue; fused epilogue + carries.
#define BM 256
#define BN 128
#define BK 64
// buffer k (k=0,1) at dsm + k*65536: X 32KB @ +0, W 32KB @ +32768

__global__ __launch_bounds__(512, 2)
void gates_gemm(const float* __restrict__ x,
                const int* __restrict__ s,
                const uint16_t* __restrict__ wt,
                const float* __restrict__ ig_b,
                const float* __restrict__ ag_b,
                const float* __restrict__ cvec,
                uint32_t* __restrict__ lanx,
                float* __restrict__ cA,
                float* __restrict__ cB) {
  extern __shared__ __align__(16) unsigned char dsm[];  // 131072 B
  __shared__ unsigned char resetm[BM];

  const int b = blockIdx.x;                    // 0..1023
  const int orig = (b & 7) * 128 + (b >> 3);   // XCD-chunked: one head per XCD
  const int h  = orig >> 7;
  const int rem = orig & 127;
  const int mt = rem >> 2;                     // 0..31
  const int nt = rem & 3;                      // 0..3
  const int m0 = mt * BM;
  const int j0 = nt * BN;

  const int tid = threadIdx.x;
  const int lane = tid & 63;
  const int w = tid >> 6;       // 0..7
  const int wr = w >> 1;        // 0..3 (M)
  const int wc = w & 1;         // 0..1 (N)
  const int lrow = lane & 15;
  const int lkg  = lane >> 4;

  if (tid < BM) {
    int n = m0 + tid;
    resetm[tid] = (n == 0) || (s[n] != s[n - 1]);
  }

  // --- X staging geometry (f32 source, bf16 swizzled LDS dest) ---
  const int xrow = tid >> 1;                   // 0..255
  const int xhalf = tid & 1;
  const float* xrow_ptr = x + (size_t)(m0 + xrow) * WIDTH + h * BW + xhalf * 32;
  uint32_t xw_addr[4];
  #pragma unroll
  for (int q = 0; q < 4; q++) {
    uint32_t o = (uint32_t)(tid * 64 + q * 16);
    xw_addr[q] = o ^ (uint32_t)((xrow & 7) << 4);
  }

  // --- W staging: source pre-swizzled, LDS linear (global_load_lds) ---
  const char* w_src[4];
  #pragma unroll
  for (int i = 0; i < 4; i++) {
    int o = (4 * w + i) * 1024 + (lane << 4);      // [0,32768)
    int g = o >> 14;                               // 0..1
    int jl = (o >> 7) & 127;
    int c = (o & 127) ^ ((jl & 7) << 4);
    w_src[i] = (const char*)wt + ((size_t)((g * 8 + h) * BW + (j0 + jl))) * (BW * 2) + c;
  }

  f32x4 acc[2][4][4];
  #pragma unroll
  for (int g = 0; g < 2; g++)
    #pragma unroll
    for (int mf = 0; mf < 4; mf++)
      #pragma unroll
      for (int nf = 0; nf < 4; nf++)
        acc[g][mf][nf] = (f32x4){0.f, 0.f, 0.f, 0.f};

  // prologue: stage slice p0 into buffer 0
  {
    const int p0 = (2 * nt + 2) & 7;
    const float* xp = xrow_ptr + p0 * 64;
    float4 xf[8];
    #pragma unroll
    for (int q = 0; q < 4; q++) {
      xf[2 * q]     = *reinterpret_cast<const float4*>(xp + q * 8);
      xf[2 * q + 1] = *reinterpret_cast<const float4*>(xp + q * 8 + 4);
    }
    #pragma unroll
    for (int i = 0; i < 4; i++)
      gload_lds16(w_src[i] + p0 * 128, dsm + 32768 + (4 * w + i) * 1024);
    #pragma unroll
    for (int q = 0; q < 4; q++) {
      uint4 v;
      v.x = pack2(xf[2 * q].x,     xf[2 * q].y);
      v.y = pack2(xf[2 * q].z,     xf[2 * q].w);
      v.z = pack2(xf[2 * q + 1].x, xf[2 * q + 1].y);
      v.w = pack2(xf[2 * q + 1].z, xf[2 * q + 1].w);
      *reinterpret_cast<uint4*>(dsm + xw_addr[q]) = v;
    }
  }
  __syncthreads();

  for (int i = 0; i < 8; i++) {
    const uint32_t cbase = (uint32_t)(i & 1) << 16;
    const uint32_t nbase = cbase ^ 65536u;
    float4 xf[8];
    if (i < 7) {  // issue next-slice loads BEFORE compute (latency overlap)
      const int p = (2 * nt + 3 + i) & 7;
      const float* xp = xrow_ptr + p * 64;
      #pragma unroll
      for (int q = 0; q < 4; q++) {
        xf[2 * q]     = *reinterpret_cast<const float4*>(xp + q * 8);
        xf[2 * q + 1] = *reinterpret_cast<const float4*>(xp + q * 8 + 4);
      }
      #pragma unroll
      for (int q = 0; q < 4; q++)
        gload_lds16(w_src[q] + p * 128, dsm + nbase + 32768 + (4 * w + q) * 1024);
    }
    #pragma unroll
    for (int ks = 0; ks < 2; ks++) {
      bf16x8 af[4];
      #pragma unroll
      for (int mf = 0; mf < 4; mf++) {
        int row = wr * 64 + 16 * mf + lrow;
        uint32_t addr = cbase + (uint32_t)((row << 7) + ks * 64 + lkg * 16);
        addr ^= (uint32_t)((row & 7) << 4);
        af[mf] = *reinterpret_cast<const bf16x8*>(dsm + addr);
      }
      #pragma unroll
      for (int g = 0; g < 2; g++) {
        #pragma unroll
        for (int nf = 0; nf < 4; nf++) {
          int j = wc * 64 + 16 * nf + lrow;
          uint32_t addr = cbase + (uint32_t)(32768 + (g << 14) + (j << 7) + ks * 64 + lkg * 16);
          addr ^= (uint32_t)((j & 7) << 4);
          bf16x8 bfr = *reinterpret_cast<const bf16x8*>(dsm + addr);
          #pragma unroll
          for (int mf = 0; mf < 4; mf++) {
            acc[g][mf][nf] = __builtin_amdgcn_mfma_f32_16x16x32_bf16(
                af[mf], bfr, acc[g][mf][nf], 0, 0, 0);
          }
        }
      }
    }
    if (i < 7) {  // convert + write next X slice into the other buffer
      #pragma unroll
      for (int q = 0; q < 4; q++) {
        uint4 v;
        v.x = pack2(xf[2 * q].x,     xf[2 * q].y);
        v.y = pack2(xf[2 * q].z,     xf[2 * q].w);
        v.z = pack2(xf[2 * q + 1].x, xf[2 * q + 1].y);
        v.w = pack2(xf[2 * q + 1].z, xf[2 * q + 1].w);
        *reinterpret_cast<uint4*>(dsm + nbase + xw_addr[q]) = v;
      }
    }
    __syncthreads();
  }
  // After the loop: buf0 X = slice 2nt (cols j0..j0+63), buf1 X = slice 2nt+1.

  float* smf = (float*)(dsm + 98304);  // buf1 W region: [4][128] A, [4][128] B

  #pragma unroll
  for (int nf = 0; nf < 4; nf++) {
    int jl = wc * 64 + 16 * nf + lrow;   // 0..127
    int jj = h * BW + j0 + jl;
    const uint32_t xsl = (uint32_t)(jl >> 6) << 16;
    const int cc2 = (jl & 63) * 2;
    float igb = ig_b[jj], agb = ag_b[jj], cv = cvec[jj];
    float segA[4], segB[4];
    #pragma unroll
    for (int mf = 0; mf < 4; mf++) {
      float A = 1.f, B = 0.f;
      int rbase = wr * 64 + 16 * mf + 4 * lkg;
      #pragma unroll
      for (int r = 0; r < 4; r++) {
        int row = rbase + r;
        int n = m0 + row;
        size_t o = (size_t)n * WIDTH + jj;
        float yig = acc[0][mf][nf][r] + igb;
        float yag = acc[1][mf][nf][r] + agb;
        float gx = __builtin_amdgcn_rcpf(1.f + __expf(-yig));
        float ga = __builtin_amdgcn_rcpf(1.f + __expf(-yag));
        float la = -ga * cv;
        uint32_t la_bits = rne_bf16(la);
        float la_r = bf16_to_f32(la_bits);
        float a = __expf(la_r);
        float mult = resetm[row] ? 1.f
                     : __builtin_amdgcn_sqrtf(fmaxf(1.f - a * a, 0.f));
        uint32_t xaddr = xsl + ((uint32_t)((row << 7) + cc2) ^ (uint32_t)((row & 7) << 4));
        float xv = bf16_to_f32(*reinterpret_cast<const uint16_t*>(dsm + xaddr));
        float nx = xv * gx * mult;
        uint32_t nx_bits = rne_bf16(nx);
        float nx_r = bf16_to_f32(nx_bits);
        lanx[o] = la_bits | (nx_bits << 16);
        A *= a;
        B = fmaf(a, B, nx_r);
      }
      segA[mf] = A; segB[mf] = B;
    }
    // combine across lkg (4 segments, stride-16 lanes), order = lkg ascending
    #pragma unroll
    for (int mf = 0; mf < 4; mf++) {
      float A = segA[mf], B = segB[mf];
      #pragma unroll
      for (int d = 16; d <= 32; d <<= 1) {
        float pA = __shfl_xor(A, d, 64);
        float pB = __shfl_xor(B, d, 64);
        bool up = (lane & d) != 0;
        B = up ? fmaf(A, pB, B) : fmaf(pA, B, pB);
        A *= pA;
      }
      segA[mf] = A; segB[mf] = B;
    }
    // serial combine across mf (row order) -> per-wave 64-row carry
    float colA = segA[0], colB = segB[0];
    #pragma unroll
    for (int mf = 1; mf < 4; mf++) {
      colB = fmaf(segA[mf], colB, segB[mf]);
      colA *= segA[mf];
    }
    if (lkg == 0) {
      int clocal = wc * 64 + 16 * nf + lrow;
      smf[wr * 128 + clocal] = colA;
      smf[512 + wr * 128 + clocal] = colB;
    }
  }
  __syncthreads();
  if (tid < 256) {
    int half = tid >> 7;        // 0: rows 0-127 (wr0,1), 1: rows 128-255 (wr2,3)
    int cl = tid & 127;
    int base = half * 2;
    float A0 = smf[base * 128 + cl],       B0 = smf[512 + base * 128 + cl];
    float A1 = smf[(base + 1) * 128 + cl], B1 = smf[512 + (base + 1) * 128 + cl];
    float Af = A0 * A1;
    float Bf = fmaf(A1, B0, B1);
    int ct = mt * 2 + half;
    int jj = h * BW + j0 + cl;
    cA[ct * WIDTH + jj] = Af;
    cB[ct * WIDTH + jj] = Bf;
  }
}

// ---- scan phase B: prefix over chunks ----
__global__ void scan_prefix(const float* __restrict__ cA, const float* __restrict__ cB,
                            float* __restrict__ prefix) {
  int c = blockIdx.x * 256 + threadIdx.x;
  float hcur = 0.f;
  for (int i0 = 0; i0 < NCHUNK; i0 += 8) {
    float av[8], bv[8];
    #pragma unroll
    for (int e = 0; e < 8; e++) { av[e] = cA[(i0 + e) * WIDTH + c]; bv[e] = cB[(i0 + e) * WIDTH + c]; }
    #pragma unroll
    for (int e = 0; e < 8; e++) { prefix[(i0 + e) * WIDTH + c] = hcur; hcur = av[e] * hcur + bv[e]; }
  }
}

// ---- scan phase C: apply (packed la|nx in, f32 out) ----
__global__ void scan_apply(const uint32_t* __restrict__ lanx,
                           const float* __restrict__ prefix,
                           float* __restrict__ out) {
  int chunk = blockIdx.x;
  int c0 = (blockIdx.y * 256 + threadIdx.x) * 4;
  size_t base = (size_t)chunk * CS * WIDTH + c0;
  float h[4];
  #pragma unroll
  for (int q = 0; q < 4; q++) h[q] = prefix[chunk * WIDTH + c0 + q];
  for (int rb = 0; rb < CS; rb += 4) {
    uint4 v[4];
    #pragma unroll
    for (int e = 0; e < 4; e++)
      v[e] = *reinterpret_cast<const uint4*>(lanx + base + (size_t)(rb + e) * WIDTH);
    #pragma unroll
    for (int e = 0; e < 4; e++) {
      float4 ov;
      h[0] = fmaf(__expf(bf16_to_f32(v[e].x & 0xffffu)), h[0], bf16_to_f32(v[e].x >> 16)); ov.x = h[0];
      h[1] = fmaf(__expf(bf16_to_f32(v[e].y & 0xffffu)), h[1], bf16_to_f32(v[e].y >> 16)); ov.y = h[1];
      h[2] = fmaf(__expf(bf16_to_f32(v[e].z & 0xffffu)), h[2], bf16_to_f32(v[e].z >> 16)); ov.z = h[2];
      h[3] = fmaf(__expf(bf16_to_f32(v[e].w & 0xffffu)), h[3], bf16_to_f32(v[e].w >> 16)); ov.w = h[3];
      *reinterpret_cast<float4*>(out + base + (size_t)(rb + e) * WIDTH) = ov;
    }
  }
}

extern "C" void kernel_launch(void* const* d_in, const int* in_sizes, int n_in,
                              void* d_out, int out_size, void* d_ws, size_t ws_size,
                              hipStream_t stream) {
  const float* x       = (const float*)d_in[0];
  const int*   s       = (const int*)d_in[1];
  const float* a_param = (const float*)d_in[2];
  const float* ig_w    = (const float*)d_in[3];
  const float* ig_b    = (const float*)d_in[4];
  const float* ag_w    = (const float*)d_in[5];
  const float* ag_b    = (const float*)d_in[6];
  float* out = (float*)d_out;
  char* ws = (char*)d_ws;

  uint32_t* lanx   = (uint32_t*)ws;                     // 134217728 B
  uint16_t* wt     = (uint16_t*)(ws + 134217728);       //   8388608 B
  float*    cvec   = (float*)(ws + 142606336);          //     16384 B
  float*    cA     = (float*)(ws + 142622720);          //   1048576 B
  float*    cB     = (float*)(ws + 143671296);          //   1048576 B
  float*    prefix = (float*)(ws + 144719872);          //   1048576 B

  prep_weights<<<dim3(16, 16, 16), 256, 0, stream>>>(ig_w, ag_w, wt);
  prep_misc<<<dim3(16), 256, 0, stream>>>(a_param, cvec);
  gates_gemm<<<dim3(1024), dim3(512), 131072, stream>>>(x, s, wt, ig_b, ag_b, cvec,
                                                        lanx, cA, cB);
  scan_prefix<<<dim3(16), 256, 0, stream>>>(cA, cB, prefix);
  scan_apply<<<dim3(NCHUNK, 4), 256, 0, stream>>>(lanx, prefix, out);
}

// Round 6
// 236.117 us; speedup vs baseline: 1.0157x; 1.0157x over previous
//
#include <hip/hip_runtime.h>
#include <hip/hip_bf16.h>
#include <stdint.h>

#define WIDTH 4096
#define NROWS 8192
#define NHEADS 8
#define BW 512
#define CS 128
#define NCHUNK (NROWS/CS)

typedef short bf16x8 __attribute__((ext_vector_type(8)));
typedef float f32x4 __attribute__((ext_vector_type(4)));

__device__ __forceinline__ uint32_t rne_bf16(float f) {
  uint32_t u = __float_as_uint(f);
  return (u + 0x7fffu + ((u >> 16) & 1u)) >> 16;
}
__device__ __forceinline__ uint32_t pack2(float lo, float hi) {
  return rne_bf16(lo) | (rne_bf16(hi) << 16);
}
__device__ __forceinline__ float bf16_to_f32(uint32_t bits) {
  return __uint_as_float(bits << 16);
}

__device__ __forceinline__ void gload_lds16(const void* g, void* l) {
  __builtin_amdgcn_global_load_lds(
      (const __attribute__((address_space(1))) void*)g,
      (__attribute__((address_space(3))) void*)l, 16, 0, 0);
}

// ---- prep: x f32 -> bf16 ----
__global__ void prep_xbf16(const float* __restrict__ x, uint16_t* __restrict__ xb) {
  size_t i = ((size_t)blockIdx.x * 256 + threadIdx.x) * 8;
  float4 f0 = *reinterpret_cast<const float4*>(x + i);
  float4 f1 = *reinterpret_cast<const float4*>(x + i + 4);
  uint4 v;
  v.x = pack2(f0.x, f0.y); v.y = pack2(f0.z, f0.w);
  v.z = pack2(f1.x, f1.y); v.w = pack2(f1.z, f1.w);
  *reinterpret_cast<uint4*>(xb + i) = v;
}

// ---- prep: transpose weights f32 [h][i][j] -> bf16 [g*8+h][j][i] ----
__global__ void prep_weights(const float* __restrict__ ig_w,
                             const float* __restrict__ ag_w,
                             uint16_t* __restrict__ wt) {
  __shared__ float tile[32][33];
  int j0 = blockIdx.x * 32;
  int i0 = blockIdx.y * 32;
  int m  = blockIdx.z;  // g*8+h
  const float* src = ((m >> 3) ? ag_w : ig_w) + (size_t)(m & 7) * BW * BW;
  int tx = threadIdx.x & 31, ty = threadIdx.x >> 5;
  #pragma unroll
  for (int k = 0; k < 4; k++) {
    int i = i0 + ty + 8 * k;
    tile[ty + 8 * k][tx] = src[(size_t)i * BW + (j0 + tx)];
  }
  __syncthreads();
  #pragma unroll
  for (int k = 0; k < 4; k++) {
    int j = j0 + ty + 8 * k;
    wt[((size_t)m * BW + j) * BW + (i0 + tx)] = (uint16_t)rne_bf16(tile[tx][ty + 8 * k]);
  }
}

__global__ void prep_misc(const float* __restrict__ a_param, float* __restrict__ cvec) {
  int i = blockIdx.x * 256 + threadIdx.x;
  if (i < WIDTH) {
    float x = a_param[i];
    float sp = (x > 15.f) ? x : log1pf(expf(x));
    cvec[i] = 8.f * sp;
  }
}

// ---- GEMM: dual-gate bf16 MFMA, tile 256x128, BK=64, 512 thr, dbuf LDS,
//      all-async staging (round-4 structure), rotated K order so the output
//      X-slices (cols 2nt, 2nt+1) end resident in LDS for the epilogue.
#define BM 256
#define BN 128
#define BK 64
// buffer k (k=0,1) at dsm + k*65536: X 32KB @ +0, W 32KB @ +32768

__global__ __launch_bounds__(512, 2)
void gates_gemm(const uint16_t* __restrict__ xb,
                const int* __restrict__ s,
                const uint16_t* __restrict__ wt,
                const float* __restrict__ ig_b,
                const float* __restrict__ ag_b,
                const float* __restrict__ cvec,
                uint32_t* __restrict__ lanx,
                float* __restrict__ cA,
                float* __restrict__ cB) {
  extern __shared__ __align__(16) unsigned char dsm[];  // 131072 B
  __shared__ unsigned char resetm[BM];

  const int b = blockIdx.x;                    // 0..1023
  const int orig = (b & 7) * 128 + (b >> 3);   // XCD-chunked: one head per XCD
  const int h  = orig >> 7;
  const int rem = orig & 127;
  const int mt = rem >> 2;                     // 0..31
  const int nt = rem & 3;                      // 0..3
  const int m0 = mt * BM;
  const int j0 = nt * BN;

  const int tid = threadIdx.x;
  const int lane = tid & 63;
  const int w = tid >> 6;       // 0..7
  const int wr = w >> 1;        // 0..3 (M)
  const int wc = w & 1;         // 0..1 (N)
  const int lrow = lane & 15;
  const int lkg  = lane >> 4;

  if (tid < BM) {
    int n = m0 + tid;
    resetm[tid] = (n == 0) || (s[n] != s[n - 1]);
  }

  // per-lane pre-swizzled global source pointers (swizzle on source, LDS linear)
  const char* xb_src[4];
  #pragma unroll
  for (int i = 0; i < 4; i++) {
    int o = (4 * w + i) * 1024 + (lane << 4);      // [0,32768)
    int row = o >> 7;                              // 0..255
    int c = (o & 127) ^ ((row & 7) << 4);
    xb_src[i] = (const char*)xb + (size_t)(m0 + row) * (WIDTH * 2) + h * (BW * 2) + c;
  }
  const char* w_src[4];
  #pragma unroll
  for (int i = 0; i < 4; i++) {
    int o = (4 * w + i) * 1024 + (lane << 4);      // [0,32768)
    int g = o >> 14;                               // 0..1
    int jl = (o >> 7) & 127;
    int c = (o & 127) ^ ((jl & 7) << 4);
    w_src[i] = (const char*)wt + ((size_t)((g * 8 + h) * BW + (j0 + jl))) * (BW * 2) + c;
  }

  f32x4 acc[2][4][4];
  #pragma unroll
  for (int g = 0; g < 2; g++)
    #pragma unroll
    for (int mf = 0; mf < 4; mf++)
      #pragma unroll
      for (int nf = 0; nf < 4; nf++)
        acc[g][mf][nf] = (f32x4){0.f, 0.f, 0.f, 0.f};

  // prologue: stage slice p0 into buffer 0
  {
    const int p0 = (2 * nt + 2) & 7;
    #pragma unroll
    for (int i = 0; i < 4; i++)
      gload_lds16(xb_src[i] + p0 * 128, dsm + (4 * w + i) * 1024);
    #pragma unroll
    for (int i = 0; i < 4; i++)
      gload_lds16(w_src[i] + p0 * 128, dsm + 32768 + (4 * w + i) * 1024);
  }
  __syncthreads();  // drains vmcnt

  for (int kt = 0; kt < 8; kt++) {
    const uint32_t cbase = (uint32_t)(kt & 1) << 16;
    if (kt < 7) {  // issue next-slice staging BEFORE compute (overlap)
      const uint32_t nbase = cbase ^ 65536u;
      const int p = (2 * nt + 3 + kt) & 7;
      #pragma unroll
      for (int i = 0; i < 4; i++)
        gload_lds16(xb_src[i] + p * 128, dsm + nbase + (4 * w + i) * 1024);
      #pragma unroll
      for (int i = 0; i < 4; i++)
        gload_lds16(w_src[i] + p * 128, dsm + nbase + 32768 + (4 * w + i) * 1024);
    }
    #pragma unroll
    for (int ks = 0; ks < 2; ks++) {
      bf16x8 af[4];
      #pragma unroll
      for (int mf = 0; mf < 4; mf++) {
        int row = wr * 64 + 16 * mf + lrow;
        uint32_t addr = cbase + (uint32_t)((row << 7) + ks * 64 + lkg * 16);
        addr ^= (uint32_t)((row & 7) << 4);
        af[mf] = *reinterpret_cast<const bf16x8*>(dsm + addr);
      }
      #pragma unroll
      for (int g = 0; g < 2; g++) {
        #pragma unroll
        for (int nf = 0; nf < 4; nf++) {
          int j = wc * 64 + 16 * nf + lrow;
          uint32_t addr = cbase + (uint32_t)(32768 + (g << 14) + (j << 7) + ks * 64 + lkg * 16);
          addr ^= (uint32_t)((j & 7) << 4);
          bf16x8 bfr = *reinterpret_cast<const bf16x8*>(dsm + addr);
          #pragma unroll
          for (int mf = 0; mf < 4; mf++) {
            acc[g][mf][nf] = __builtin_amdgcn_mfma_f32_16x16x32_bf16(
                af[mf], bfr, acc[g][mf][nf], 0, 0, 0);
          }
        }
      }
    }
    __syncthreads();  // drains next-tile loads; protects buffer reuse
  }
  // After the loop: buf0 X = slice 2nt (cols j0..j0+63), buf1 X = slice 2nt+1.

  float* smf = (float*)(dsm + 98304);  // buf1 W region: [4][128] A, [4][128] B

  #pragma unroll
  for (int nf = 0; nf < 4; nf++) {
    int jl = wc * 64 + 16 * nf + lrow;   // 0..127
    int jj = h * BW + j0 + jl;
    const uint32_t xsl = (uint32_t)(jl >> 6) << 16;
    const int cc2 = (jl & 63) * 2;
    float igb = ig_b[jj], agb = ag_b[jj], cv = cvec[jj];
    float segA[4], segB[4];
    #pragma unroll
    for (int mf = 0; mf < 4; mf++) {
      float A = 1.f, B = 0.f;
      int rbase = wr * 64 + 16 * mf + 4 * lkg;
      #pragma unroll
      for (int r = 0; r < 4; r++) {
        int row = rbase + r;
        int n = m0 + row;
        size_t o = (size_t)n * WIDTH + jj;
        float yig = acc[0][mf][nf][r] + igb;
        float yag = acc[1][mf][nf][r] + agb;
        float gx = __builtin_amdgcn_rcpf(1.f + __expf(-yig));
        float ga = __builtin_amdgcn_rcpf(1.f + __expf(-yag));
        float la = -ga * cv;
        uint32_t la_bits = rne_bf16(la);
        float la_r = bf16_to_f32(la_bits);
        float a = __expf(la_r);
        float mult = resetm[row] ? 1.f
                     : __builtin_amdgcn_sqrtf(fmaxf(1.f - a * a, 0.f));
        uint32_t xaddr = xsl + ((uint32_t)((row << 7) + cc2) ^ (uint32_t)((row & 7) << 4));
        float xv = bf16_to_f32(*reinterpret_cast<const uint16_t*>(dsm + xaddr));
        float nx = xv * gx * mult;
        uint32_t nx_bits = rne_bf16(nx);
        float nx_r = bf16_to_f32(nx_bits);
        lanx[o] = la_bits | (nx_bits << 16);
        A *= a;
        B = fmaf(a, B, nx_r);
      }
      segA[mf] = A; segB[mf] = B;
    }
    // combine across lkg (4 segments, stride-16 lanes), order = lkg ascending
    #pragma unroll
    for (int mf = 0; mf < 4; mf++) {
      float A = segA[mf], B = segB[mf];
      #pragma unroll
      for (int d = 16; d <= 32; d <<= 1) {
        float pA = __shfl_xor(A, d, 64);
        float pB = __shfl_xor(B, d, 64);
        bool up = (lane & d) != 0;
        B = up ? fmaf(A, pB, B) : fmaf(pA, B, pB);
        A *= pA;
      }
      segA[mf] = A; segB[mf] = B;
    }
    // serial combine across mf (row order) -> per-wave 64-row carry
    float colA = segA[0], colB = segB[0];
    #pragma unroll
    for (int mf = 1; mf < 4; mf++) {
      colB = fmaf(segA[mf], colB, segB[mf]);
      colA *= segA[mf];
    }
    if (lkg == 0) {
      int clocal = wc * 64 + 16 * nf + lrow;
      smf[wr * 128 + clocal] = colA;
      smf[512 + wr * 128 + clocal] = colB;
    }
  }
  __syncthreads();
  if (tid < 256) {
    int half = tid >> 7;        // 0: rows 0-127 (wr0,1), 1: rows 128-255 (wr2,3)
    int cl = tid & 127;
    int base = half * 2;
    float A0 = smf[base * 128 + cl],       B0 = smf[512 + base * 128 + cl];
    float A1 = smf[(base + 1) * 128 + cl], B1 = smf[512 + (base + 1) * 128 + cl];
    float Af = A0 * A1;
    float Bf = fmaf(A1, B0, B1);
    int ct = mt * 2 + half;
    int jj = h * BW + j0 + cl;
    cA[ct * WIDTH + jj] = Af;
    cB[ct * WIDTH + jj] = Bf;
  }
}

// ---- scan phase B: prefix over chunks ----
__global__ void scan_prefix(const float* __restrict__ cA, const float* __restrict__ cB,
                            float* __restrict__ prefix) {
  int c = blockIdx.x * 256 + threadIdx.x;
  float hcur = 0.f;
  for (int i0 = 0; i0 < NCHUNK; i0 += 8) {
    float av[8], bv[8];
    #pragma unroll
    for (int e = 0; e < 8; e++) { av[e] = cA[(i0 + e) * WIDTH + c]; bv[e] = cB[(i0 + e) * WIDTH + c]; }
    #pragma unroll
    for (int e = 0; e < 8; e++) { prefix[(i0 + e) * WIDTH + c] = hcur; hcur = av[e] * hcur + bv[e]; }
  }
}

// ---- scan phase C: apply (packed la|nx in, f32 out) ----
__global__ void scan_apply(const uint32_t* __restrict__ lanx,
                           const float* __restrict__ prefix,
                           float* __restrict__ out) {
  int chunk = blockIdx.x;
  int c0 = (blockIdx.y * 256 + threadIdx.x) * 4;
  size_t base = (size_t)chunk * CS * WIDTH + c0;
  float h[4];
  #pragma unroll
  for (int q = 0; q < 4; q++) h[q] = prefix[chunk * WIDTH + c0 + q];
  for (int rb = 0; rb < CS; rb += 4) {
    uint4 v[4];
    #pragma unroll
    for (int e = 0; e < 4; e++)
      v[e] = *reinterpret_cast<const uint4*>(lanx + base + (size_t)(rb + e) * WIDTH);
    #pragma unroll
    for (int e = 0; e < 4; e++) {
      float4 ov;
      h[0] = fmaf(__expf(bf16_to_f32(v[e].x & 0xffffu)), h[0], bf16_to_f32(v[e].x >> 16)); ov.x = h[0];
      h[1] = fmaf(__expf(bf16_to_f32(v[e].y & 0xffffu)), h[1], bf16_to_f32(v[e].y >> 16)); ov.y = h[1];
      h[2] = fmaf(__expf(bf16_to_f32(v[e].z & 0xffffu)), h[2], bf16_to_f32(v[e].z >> 16)); ov.z = h[2];
      h[3] = fmaf(__expf(bf16_to_f32(v[e].w & 0xffffu)), h[3], bf16_to_f32(v[e].w >> 16)); ov.w = h[3];
      *reinterpret_cast<float4*>(out + base + (size_t)(rb + e) * WIDTH) = ov;
    }
  }
}

extern "C" void kernel_launch(void* const* d_in, const int* in_sizes, int n_in,
                              void* d_out, int out_size, void* d_ws, size_t ws_size,
                              hipStream_t stream) {
  const float* x       = (const float*)d_in[0];
  const int*   s       = (const int*)d_in[1];
  const float* a_param = (const float*)d_in[2];
  const float* ig_w    = (const float*)d_in[3];
  const float* ig_b    = (const float*)d_in[4];
  const float* ag_w    = (const float*)d_in[5];
  const float* ag_b    = (const float*)d_in[6];
  float* out = (float*)d_out;
  char* ws = (char*)d_ws;

  uint32_t* lanx   = (uint32_t*)ws;                     // 134217728 B
  uint16_t* wt     = (uint16_t*)(ws + 134217728);       //   8388608 B
  uint16_t* xb     = (uint16_t*)(ws + 142606336);       //  67108864 B
  float*    cvec   = (float*)(ws + 209715200);          //     16384 B
  float*    cA     = (float*)(ws + 209731584);          //   1048576 B
  float*    cB     = (float*)(ws + 210780160);          //   1048576 B
  float*    prefix = (float*)(ws + 211828736);          //   1048576 B

  prep_xbf16<<<dim3(16384), 256, 0, stream>>>(x, xb);
  prep_weights<<<dim3(16, 16, 16), 256, 0, stream>>>(ig_w, ag_w, wt);
  prep_misc<<<dim3(16), 256, 0, stream>>>(a_param, cvec);
  gates_gemm<<<dim3(1024), dim3(512), 131072, stream>>>(xb, s, wt, ig_b, ag_b, cvec,
                                                        lanx, cA, cB);
  scan_prefix<<<dim3(16), 256, 0, stream>>>(cA, cB, prefix);
  scan_apply<<<dim3(NCHUNK, 4), 256, 0, stream>>>(lanx, prefix, out);
}

// Round 7
// 224.698 us; speedup vs baseline: 1.0673x; 1.0508x over previous
//
#include <hip/hip_runtime.h>
#include <hip/hip_bf16.h>
#include <stdint.h>

#define WIDTH 4096
#define NROWS 8192
#define NHEADS 8
#define BW 512
#define CS 128
#define NCHUNK (NROWS/CS)

typedef short bf16x8 __attribute__((ext_vector_type(8)));
typedef float f32x4 __attribute__((ext_vector_type(4)));

__device__ __forceinline__ uint32_t rne_bf16(float f) {
  uint32_t u = __float_as_uint(f);
  return (u + 0x7fffu + ((u >> 16) & 1u)) >> 16;
}
__device__ __forceinline__ uint32_t pack2(float lo, float hi) {
  return rne_bf16(lo) | (rne_bf16(hi) << 16);
}
__device__ __forceinline__ float bf16_to_f32(uint32_t bits) {
  return __uint_as_float(bits << 16);
}

__device__ __forceinline__ void gload_lds16(const void* g, void* l) {
  __builtin_amdgcn_global_load_lds(
      (const __attribute__((address_space(1))) void*)g,
      (__attribute__((address_space(3))) void*)l, 16, 0, 0);
}

// ---- prep: x f32 -> bf16 ----
__global__ void prep_xbf16(const float* __restrict__ x, uint16_t* __restrict__ xb) {
  size_t i = ((size_t)blockIdx.x * 256 + threadIdx.x) * 8;
  float4 f0 = *reinterpret_cast<const float4*>(x + i);
  float4 f1 = *reinterpret_cast<const float4*>(x + i + 4);
  uint4 v;
  v.x = pack2(f0.x, f0.y); v.y = pack2(f0.z, f0.w);
  v.z = pack2(f1.x, f1.y); v.w = pack2(f1.z, f1.w);
  *reinterpret_cast<uint4*>(xb + i) = v;
}

// ---- prep: transpose weights f32 [h][i][j] -> bf16 [g*8+h][j][i] ----
__global__ void prep_weights(const float* __restrict__ ig_w,
                             const float* __restrict__ ag_w,
                             uint16_t* __restrict__ wt) {
  __shared__ float tile[32][33];
  int j0 = blockIdx.x * 32;
  int i0 = blockIdx.y * 32;
  int m  = blockIdx.z;  // g*8+h
  const float* src = ((m >> 3) ? ag_w : ig_w) + (size_t)(m & 7) * BW * BW;
  int tx = threadIdx.x & 31, ty = threadIdx.x >> 5;
  #pragma unroll
  for (int k = 0; k < 4; k++) {
    int i = i0 + ty + 8 * k;
    tile[ty + 8 * k][tx] = src[(size_t)i * BW + (j0 + tx)];
  }
  __syncthreads();
  #pragma unroll
  for (int k = 0; k < 4; k++) {
    int j = j0 + ty + 8 * k;
    wt[((size_t)m * BW + j) * BW + (i0 + tx)] = (uint16_t)rne_bf16(tile[tx][ty + 8 * k]);
  }
}

__global__ void prep_misc(const float* __restrict__ a_param, float* __restrict__ cvec) {
  int i = blockIdx.x * 256 + threadIdx.x;
  if (i < WIDTH) {
    float x = a_param[i];
    float sp = (x > 15.f) ? x : log1pf(expf(x));
    cvec[i] = 8.f * sp;
  }
}

// ---- GEMM: dual-gate bf16 MFMA, tile 128x64, BK=64, 256 thr, single-buffer
//      LDS (32 KB -> ~4 blocks/CU, m97-style cross-block overlap), rotated K
//      order so the output X slice (= slice nt) is LDS-resident at epilogue.
#define BM 128
#define BN 64
#define BK 64
// LDS: X [128][64]bf16 swizzled @0 (16 KB), W [2][64][64]bf16 @16384 (16 KB)

__global__ __launch_bounds__(256, 4)
void gates_gemm(const uint16_t* __restrict__ xb,
                const int* __restrict__ s,
                const uint16_t* __restrict__ wt,
                const float* __restrict__ ig_b,
                const float* __restrict__ ag_b,
                const float* __restrict__ cvec,
                uint32_t* __restrict__ lanx,
                float* __restrict__ cA,
                float* __restrict__ cB) {
  __shared__ __align__(16) unsigned char dsm[32768];
  __shared__ unsigned char resetm[BM];

  const int b = blockIdx.x;                    // 0..4095
  const int orig = (b & 7) * 512 + (b >> 3);   // XCD-chunked: one head per XCD
  const int h  = orig >> 9;
  const int rem = orig & 511;
  const int mt = rem >> 3;                     // 0..63
  const int nt = rem & 7;                      // 0..7
  const int m0 = mt * BM;
  const int j0 = nt * BN;

  const int tid = threadIdx.x;
  const int lane = tid & 63;
  const int w = tid >> 6;       // 0..3
  const int wr = w >> 1;        // 0..1 (M: 64-row halves)
  const int wc = w & 1;         // 0..1 (N: 32-col halves)
  const int lrow = lane & 15;
  const int lkg  = lane >> 4;

  if (tid < BM) {
    int n = m0 + tid;
    resetm[tid] = (n == 0) || (s[n] != s[n - 1]);
  }

  // per-lane pre-swizzled global source pointers (swizzle on source, LDS linear)
  const char* xb_src[4];
  #pragma unroll
  for (int i = 0; i < 4; i++) {
    int o = i * 4096 + tid * 16;                   // [0,16384)
    int row = o >> 7;                              // 0..127
    int c = (o & 127) ^ ((row & 7) << 4);
    xb_src[i] = (const char*)xb + (size_t)(m0 + row) * (WIDTH * 2) + h * (BW * 2) + c;
  }
  const char* w_src[4];
  #pragma unroll
  for (int i = 0; i < 4; i++) {
    int o = i * 4096 + tid * 16;                   // [0,16384)
    int g = o >> 13;                               // 0..1
    int jl = (o >> 7) & 63;
    int c = (o & 127) ^ ((jl & 7) << 4);
    w_src[i] = (const char*)wt + ((size_t)((g * 8 + h) * BW + (j0 + jl))) * (BW * 2) + c;
  }

  f32x4 acc[2][4][2];
  #pragma unroll
  for (int g = 0; g < 2; g++)
    #pragma unroll
    for (int mf = 0; mf < 4; mf++)
      #pragma unroll
      for (int nf = 0; nf < 2; nf++)
        acc[g][mf][nf] = (f32x4){0.f, 0.f, 0.f, 0.f};

  for (int kt = 0; kt < 8; kt++) {
    const int p = (nt + 1 + kt) & 7;   // rotated K order; last slice = nt
    __syncthreads();                    // previous compute done
    #pragma unroll
    for (int i = 0; i < 4; i++)
      gload_lds16(xb_src[i] + p * 128, dsm + i * 4096 + tid * 16);
    #pragma unroll
    for (int i = 0; i < 4; i++)
      gload_lds16(w_src[i] + p * 128, dsm + 16384 + i * 4096 + tid * 16);
    __syncthreads();                    // drain staging
    #pragma unroll
    for (int ks = 0; ks < 2; ks++) {
      bf16x8 af[4];
      #pragma unroll
      for (int mf = 0; mf < 4; mf++) {
        int row = wr * 64 + 16 * mf + lrow;
        uint32_t addr = (uint32_t)((row << 7) + ks * 64 + lkg * 16);
        addr ^= (uint32_t)((row & 7) << 4);
        af[mf] = *reinterpret_cast<const bf16x8*>(dsm + addr);
      }
      #pragma unroll
      for (int g = 0; g < 2; g++) {
        #pragma unroll
        for (int nf = 0; nf < 2; nf++) {
          int j = wc * 32 + 16 * nf + lrow;
          uint32_t addr = (uint32_t)(16384 + (g << 13) + (j << 7) + ks * 64 + lkg * 16);
          addr ^= (uint32_t)((j & 7) << 4);
          bf16x8 bfr = *reinterpret_cast<const bf16x8*>(dsm + addr);
          #pragma unroll
          for (int mf = 0; mf < 4; mf++) {
            acc[g][mf][nf] = __builtin_amdgcn_mfma_f32_16x16x32_bf16(
                af[mf], bfr, acc[g][mf][nf], 0, 0, 0);
          }
        }
      }
    }
  }
  __syncthreads();  // all waves done reading W region; X region stays read-only
  // X slice nt (cols j0..j0+63) is resident in dsm[0,16384).

  float* smf = (float*)(dsm + 16384);  // reuse W region: [2][64] A, then B @+128

  #pragma unroll
  for (int nf = 0; nf < 2; nf++) {
    int jl = wc * 32 + 16 * nf + lrow;   // 0..63
    int jj = h * BW + j0 + jl;
    const int cc2 = jl * 2;
    float igb = ig_b[jj], agb = ag_b[jj], cv = cvec[jj];
    float segA[4], segB[4];
    #pragma unroll
    for (int mf = 0; mf < 4; mf++) {
      float A = 1.f, B = 0.f;
      int rbase = wr * 64 + 16 * mf + 4 * lkg;
      #pragma unroll
      for (int r = 0; r < 4; r++) {
        int row = rbase + r;
        int n = m0 + row;
        size_t o = (size_t)n * WIDTH + jj;
        float yig = acc[0][mf][nf][r] + igb;
        float yag = acc[1][mf][nf][r] + agb;
        float gx = __builtin_amdgcn_rcpf(1.f + __expf(-yig));
        float ga = __builtin_amdgcn_rcpf(1.f + __expf(-yag));
        float la = -ga * cv;
        uint32_t la_bits = rne_bf16(la);
        float la_r = bf16_to_f32(la_bits);
        float a = __expf(la_r);
        float mult = resetm[row] ? 1.f
                     : __builtin_amdgcn_sqrtf(fmaxf(1.f - a * a, 0.f));
        uint32_t xaddr = (uint32_t)((row << 7) + cc2) ^ (uint32_t)((row & 7) << 4);
        float xv = bf16_to_f32(*reinterpret_cast<const uint16_t*>(dsm + xaddr));
        float nx = xv * gx * mult;
        uint32_t nx_bits = rne_bf16(nx);
        float nx_r = bf16_to_f32(nx_bits);
        lanx[o] = la_bits | (nx_bits << 16);
        A *= a;
        B = fmaf(a, B, nx_r);
      }
      segA[mf] = A; segB[mf] = B;
    }
    // combine across lkg (4 segments, stride-16 lanes), order = lkg ascending
    #pragma unroll
    for (int mf = 0; mf < 4; mf++) {
      float A = segA[mf], B = segB[mf];
      #pragma unroll
      for (int d = 16; d <= 32; d <<= 1) {
        float pA = __shfl_xor(A, d, 64);
        float pB = __shfl_xor(B, d, 64);
        bool up = (lane & d) != 0;
        B = up ? fmaf(A, pB, B) : fmaf(pA, B, pB);
        A *= pA;
      }
      segA[mf] = A; segB[mf] = B;
    }
    // serial combine across mf (row order) -> per-wave 64-row carry
    float colA = segA[0], colB = segB[0];
    #pragma unroll
    for (int mf = 1; mf < 4; mf++) {
      colB = fmaf(segA[mf], colB, segB[mf]);
      colA *= segA[mf];
    }
    if (lkg == 0) {
      int clocal = wc * 32 + 16 * nf + lrow;
      smf[wr * 64 + clocal] = colA;
      smf[128 + wr * 64 + clocal] = colB;
    }
  }
  __syncthreads();
  if (tid < BN) {
    float A0 = smf[tid],       B0 = smf[128 + tid];
    float A1 = smf[64 + tid],  B1 = smf[192 + tid];
    float Af = A0 * A1;
    float Bf = fmaf(A1, B0, B1);
    int jj = h * BW + j0 + tid;
    cA[mt * WIDTH + jj] = Af;   // chunk index == mt (BM == CS)
    cB[mt * WIDTH + jj] = Bf;
  }
}

// ---- scan phase B: prefix over chunks ----
__global__ void scan_prefix(const float* __restrict__ cA, const float* __restrict__ cB,
                            float* __restrict__ prefix) {
  int c = blockIdx.x * 256 + threadIdx.x;
  float hcur = 0.f;
  for (int i0 = 0; i0 < NCHUNK; i0 += 8) {
    float av[8], bv[8];
    #pragma unroll
    for (int e = 0; e < 8; e++) { av[e] = cA[(i0 + e) * WIDTH + c]; bv[e] = cB[(i0 + e) * WIDTH + c]; }
    #pragma unroll
    for (int e = 0; e < 8; e++) { prefix[(i0 + e) * WIDTH + c] = hcur; hcur = av[e] * hcur + bv[e]; }
  }
}

// ---- scan phase C: apply (packed la|nx in, f32 out) ----
__global__ void scan_apply(const uint32_t* __restrict__ lanx,
                           const float* __restrict__ prefix,
                           float* __restrict__ out) {
  int chunk = blockIdx.x;
  int c0 = (blockIdx.y * 256 + threadIdx.x) * 4;
  size_t base = (size_t)chunk * CS * WIDTH + c0;
  float h[4];
  #pragma unroll
  for (int q = 0; q < 4; q++) h[q] = prefix[chunk * WIDTH + c0 + q];
  for (int rb = 0; rb < CS; rb += 4) {
    uint4 v[4];
    #pragma unroll
    for (int e = 0; e < 4; e++)
      v[e] = *reinterpret_cast<const uint4*>(lanx + base + (size_t)(rb + e) * WIDTH);
    #pragma unroll
    for (int e = 0; e < 4; e++) {
      float4 ov;
      h[0] = fmaf(__expf(bf16_to_f32(v[e].x & 0xffffu)), h[0], bf16_to_f32(v[e].x >> 16)); ov.x = h[0];
      h[1] = fmaf(__expf(bf16_to_f32(v[e].y & 0xffffu)), h[1], bf16_to_f32(v[e].y >> 16)); ov.y = h[1];
      h[2] = fmaf(__expf(bf16_to_f32(v[e].z & 0xffffu)), h[2], bf16_to_f32(v[e].z >> 16)); ov.z = h[2];
      h[3] = fmaf(__expf(bf16_to_f32(v[e].w & 0xffffu)), h[3], bf16_to_f32(v[e].w >> 16)); ov.w = h[3];
      *reinterpret_cast<float4*>(out + base + (size_t)(rb + e) * WIDTH) = ov;
    }
  }
}

extern "C" void kernel_launch(void* const* d_in, const int* in_sizes, int n_in,
                              void* d_out, int out_size, void* d_ws, size_t ws_size,
                              hipStream_t stream) {
  const float* x       = (const float*)d_in[0];
  const int*   s       = (const int*)d_in[1];
  const float* a_param = (const float*)d_in[2];
  const float* ig_w    = (const float*)d_in[3];
  const float* ig_b    = (const float*)d_in[4];
  const float* ag_w    = (const float*)d_in[5];
  const float* ag_b    = (const float*)d_in[6];
  float* out = (float*)d_out;
  char* ws = (char*)d_ws;

  uint32_t* lanx   = (uint32_t*)ws;                     // 134217728 B
  uint16_t* wt     = (uint16_t*)(ws + 134217728);       //   8388608 B
  uint16_t* xb     = (uint16_t*)(ws + 142606336);       //  67108864 B
  float*    cvec   = (float*)(ws + 209715200);          //     16384 B
  float*    cA     = (float*)(ws + 209731584);          //   1048576 B
  float*    cB     = (float*)(ws + 210780160);          //   1048576 B
  float*    prefix = (float*)(ws + 211828736);          //   1048576 B

  prep_xbf16<<<dim3(16384), 256, 0, stream>>>(x, xb);
  prep_weights<<<dim3(16, 16, 16), 256, 0, stream>>>(ig_w, ag_w, wt);
  prep_misc<<<dim3(16), 256, 0, stream>>>(a_param, cvec);
  gates_gemm<<<dim3(4096), 256, 0, stream>>>(xb, s, wt, ig_b, ag_b, cvec,
                                             lanx, cA, cB);
  scan_prefix<<<dim3(16), 256, 0, stream>>>(cA, cB, prefix);
  scan_apply<<<dim3(NCHUNK, 4), 256, 0, stream>>>(lanx, prefix, out);
}

// Round 8
// 199.617 us; speedup vs baseline: 1.2014x; 1.1256x over previous
//
#include <hip/hip_runtime.h>
#include <hip/hip_bf16.h>
#include <stdint.h>

#define WIDTH 4096
#define NROWS 8192
#define NHEADS 8
#define BW 512
#define CS 128
#define NCHUNK (NROWS/CS)

typedef short bf16x8 __attribute__((ext_vector_type(8)));
typedef float f32x4 __attribute__((ext_vector_type(4)));

__device__ __forceinline__ uint32_t rne_bf16(float f) {
  uint32_t u = __float_as_uint(f);
  return (u + 0x7fffu + ((u >> 16) & 1u)) >> 16;
}
__device__ __forceinline__ uint32_t pack2(float lo, float hi) {
  return rne_bf16(lo) | (rne_bf16(hi) << 16);
}
__device__ __forceinline__ float bf16_to_f32(uint32_t bits) {
  return __uint_as_float(bits << 16);
}
__device__ __forceinline__ uint32_t cvtpk(float a, float b) {
  uint32_t r;
  asm("v_cvt_pk_bf16_f32 %0, %1, %2" : "=v"(r) : "v"(a), "v"(b));
  return r;
}

__device__ __forceinline__ void gload_lds16(const void* g, void* l) {
  __builtin_amdgcn_global_load_lds(
      (const __attribute__((address_space(1))) void*)g,
      (__attribute__((address_space(3))) void*)l, 16, 0, 0);
}

// ---- prep: transpose weights f32 [h][i][j] -> bf16 [g*8+h][j][i] ----
__global__ void prep_weights(const float* __restrict__ ig_w,
                             const float* __restrict__ ag_w,
                             uint16_t* __restrict__ wt) {
  __shared__ float tile[32][33];
  int j0 = blockIdx.x * 32;
  int i0 = blockIdx.y * 32;
  int m  = blockIdx.z;  // g*8+h
  const float* src = ((m >> 3) ? ag_w : ig_w) + (size_t)(m & 7) * BW * BW;
  int tx = threadIdx.x & 31, ty = threadIdx.x >> 5;
  #pragma unroll
  for (int k = 0; k < 4; k++) {
    int i = i0 + ty + 8 * k;
    tile[ty + 8 * k][tx] = src[(size_t)i * BW + (j0 + tx)];
  }
  __syncthreads();
  #pragma unroll
  for (int k = 0; k < 4; k++) {
    int j = j0 + ty + 8 * k;
    wt[((size_t)m * BW + j) * BW + (i0 + tx)] = (uint16_t)rne_bf16(tile[tx][ty + 8 * k]);
  }
}

__global__ void prep_misc(const float* __restrict__ a_param, float* __restrict__ cvec) {
  int i = blockIdx.x * 256 + threadIdx.x;
  if (i < WIDTH) {
    float x = a_param[i];
    float sp = (x > 15.f) ? x : log1pf(expf(x));
    cvec[i] = 8.f * sp;
  }
}

// ---- GEMM: dual-gate bf16 MFMA, tile 128x64, BK=64, 256 thr, single-buffer
//      LDS, X staged as f32 (gload_lds) + cvt_pk at fragment load, rotated K
//      order so the output X slice (= slice nt) is LDS-resident at epilogue.
#define BM 128
#define BN 64
#define BK 64
// LDS: X [128][64]f32 swizzled(^row<<5) @0 (32 KB), W [2][64][64]bf16 @32768 (16 KB)

__global__ __launch_bounds__(256, 3)
void gates_gemm(const float* __restrict__ x,
                const int* __restrict__ s,
                const uint16_t* __restrict__ wt,
                const float* __restrict__ ig_b,
                const float* __restrict__ ag_b,
                const float* __restrict__ cvec,
                uint32_t* __restrict__ lanx,
                float* __restrict__ cA,
                float* __restrict__ cB) {
  __shared__ __align__(16) unsigned char dsm[49152];
  __shared__ unsigned char resetm[BM];

  const int b = blockIdx.x;                    // 0..4095
  const int orig = (b & 7) * 512 + (b >> 3);   // XCD-chunked: one head per XCD
  const int h  = orig >> 9;
  const int rem = orig & 511;
  const int mt = rem >> 3;                     // 0..63
  const int nt = rem & 7;                      // 0..7
  const int m0 = mt * BM;
  const int j0 = nt * BN;

  const int tid = threadIdx.x;
  const int lane = tid & 63;
  const int w = tid >> 6;       // 0..3
  const int wr = w >> 1;        // 0..1 (M: 64-row halves)
  const int wc = w & 1;         // 0..1 (N: 32-col halves)
  const int lrow = lane & 15;
  const int lkg  = lane >> 4;

  if (tid < BM) {
    int n = m0 + tid;
    resetm[tid] = (n == 0) || (s[n] != s[n - 1]);
  }

  // X staging: f32 source pre-swizzled (^ (row&7)<<5 within 256B row), LDS linear
  const char* x_src[8];
  #pragma unroll
  for (int i = 0; i < 8; i++) {
    int o = i * 4096 + tid * 16;                   // [0,32768)
    int row = o >> 8;                              // 0..127
    int c = (o & 255) ^ ((row & 7) << 5);
    x_src[i] = (const char*)x + ((size_t)(m0 + row) * WIDTH + h * BW) * 4 + c;
  }
  // W staging: bf16 source pre-swizzled (^ (jl&7)<<4 within 128B row), LDS linear
  const char* w_src[4];
  #pragma unroll
  for (int i = 0; i < 4; i++) {
    int o = i * 4096 + tid * 16;                   // [0,16384)
    int g = o >> 13;                               // 0..1
    int jl = (o >> 7) & 63;
    int c = (o & 127) ^ ((jl & 7) << 4);
    w_src[i] = (const char*)wt + ((size_t)((g * 8 + h) * BW + (j0 + jl))) * (BW * 2) + c;
  }

  f32x4 acc[2][4][2];
  #pragma unroll
  for (int g = 0; g < 2; g++)
    #pragma unroll
    for (int mf = 0; mf < 4; mf++)
      #pragma unroll
      for (int nf = 0; nf < 2; nf++)
        acc[g][mf][nf] = (f32x4){0.f, 0.f, 0.f, 0.f};

  for (int kt = 0; kt < 8; kt++) {
    const int p = (nt + 1 + kt) & 7;   // rotated K order; last slice = nt
    __syncthreads();                    // previous compute done
    #pragma unroll
    for (int i = 0; i < 8; i++)
      gload_lds16(x_src[i] + p * 256, dsm + i * 4096 + tid * 16);
    #pragma unroll
    for (int i = 0; i < 4; i++)
      gload_lds16(w_src[i] + p * 128, dsm + 32768 + i * 4096 + tid * 16);
    __syncthreads();                    // drain staging
    #pragma unroll
    for (int ks = 0; ks < 2; ks++) {
      bf16x8 af[4];
      #pragma unroll
      for (int mf = 0; mf < 4; mf++) {
        int row = wr * 64 + 16 * mf + lrow;
        uint32_t addr = (uint32_t)((row << 8) + ks * 128 + lkg * 32);
        addr ^= (uint32_t)((row & 7) << 5);
        f32x4 lo = *reinterpret_cast<const f32x4*>(dsm + addr);
        f32x4 hi = *reinterpret_cast<const f32x4*>(dsm + addr + 16);
        union { uint32_t u[4]; bf16x8 v; } cvu;
        cvu.u[0] = cvtpk(lo.x, lo.y);
        cvu.u[1] = cvtpk(lo.z, lo.w);
        cvu.u[2] = cvtpk(hi.x, hi.y);
        cvu.u[3] = cvtpk(hi.z, hi.w);
        af[mf] = cvu.v;
      }
      #pragma unroll
      for (int g = 0; g < 2; g++) {
        #pragma unroll
        for (int nf = 0; nf < 2; nf++) {
          int j = wc * 32 + 16 * nf + lrow;
          uint32_t addr = (uint32_t)(32768 + (g << 13) + (j << 7) + ks * 64 + lkg * 16);
          addr ^= (uint32_t)((j & 7) << 4);
          bf16x8 bfr = *reinterpret_cast<const bf16x8*>(dsm + addr);
          #pragma unroll
          for (int mf = 0; mf < 4; mf++) {
            acc[g][mf][nf] = __builtin_amdgcn_mfma_f32_16x16x32_bf16(
                af[mf], bfr, acc[g][mf][nf], 0, 0, 0);
          }
        }
      }
    }
  }
  __syncthreads();  // all waves done with W region; X region stays read-only
  // X slice nt (cols j0..j0+63, f32) is resident in dsm[0,32768).

  float* smf = (float*)(dsm + 32768);  // reuse W region: [2][64] A, then B @+128

  const int jl0 = wc * 32 + lrow;      // nf=0 col (0..63)
  float igb[2], agb[2], cv2[2];
  #pragma unroll
  for (int nf = 0; nf < 2; nf++) {
    int jj = h * BW + j0 + jl0 + 16 * nf;
    igb[nf] = ig_b[jj]; agb[nf] = ag_b[jj]; cv2[nf] = cvec[jj];
  }

  float segA[2][4], segB[2][4];
  #pragma unroll
  for (int mf = 0; mf < 4; mf++) {
    float A[2] = {1.f, 1.f}, B[2] = {0.f, 0.f};
    int rbase = wr * 64 + 16 * mf + 4 * lkg;
    #pragma unroll
    for (int r = 0; r < 4; r++) {
      int row = rbase + r;
      int n = m0 + row;
      bool rs = resetm[row] != 0;
      #pragma unroll
      for (int nf = 0; nf < 2; nf++) {   // nf inner: both 64B halves of the
        int jl = jl0 + 16 * nf;          // 128B line written time-adjacently
        size_t o = (size_t)n * WIDTH + h * BW + j0 + jl;
        float yig = acc[0][mf][nf][r] + igb[nf];
        float yag = acc[1][mf][nf][r] + agb[nf];
        float gx = __builtin_amdgcn_rcpf(1.f + __expf(-yig));
        float ga = __builtin_amdgcn_rcpf(1.f + __expf(-yag));
        float la = -ga * cv2[nf];
        uint32_t la_bits = rne_bf16(la);
        float la_r = bf16_to_f32(la_bits);
        float a = __expf(la_r);
        float mult = rs ? 1.f
                     : __builtin_amdgcn_sqrtf(fmaxf(1.f - a * a, 0.f));
        uint32_t xaddr = (uint32_t)((row << 8) + jl * 4) ^ (uint32_t)((row & 7) << 5);
        float xv = *reinterpret_cast<const float*>(dsm + xaddr);
        float nx = xv * gx * mult;
        uint32_t nx_bits = rne_bf16(nx);
        float nx_r = bf16_to_f32(nx_bits);
        lanx[o] = la_bits | (nx_bits << 16);
        A[nf] *= a;
        B[nf] = fmaf(a, B[nf], nx_r);
      }
    }
    segA[0][mf] = A[0]; segB[0][mf] = B[0];
    segA[1][mf] = A[1]; segB[1][mf] = B[1];
  }
  // combine across lkg (4 segments, stride-16 lanes), order = lkg ascending
  #pragma unroll
  for (int nf = 0; nf < 2; nf++) {
    #pragma unroll
    for (int mf = 0; mf < 4; mf++) {
      float A = segA[nf][mf], B = segB[nf][mf];
      #pragma unroll
      for (int d = 16; d <= 32; d <<= 1) {
        float pA = __shfl_xor(A, d, 64);
        float pB = __shfl_xor(B, d, 64);
        bool up = (lane & d) != 0;
        B = up ? fmaf(A, pB, B) : fmaf(pA, B, pB);
        A *= pA;
      }
      segA[nf][mf] = A; segB[nf][mf] = B;
    }
    // serial combine across mf (row order) -> per-wave 64-row carry
    float colA = segA[nf][0], colB = segB[nf][0];
    #pragma unroll
    for (int mf = 1; mf < 4; mf++) {
      colB = fmaf(segA[nf][mf], colB, segB[nf][mf]);
      colA *= segA[nf][mf];
    }
    if (lkg == 0) {
      int clocal = wc * 32 + 16 * nf + lrow;
      smf[wr * 64 + clocal] = colA;
      smf[128 + wr * 64 + clocal] = colB;
    }
  }
  __syncthreads();
  if (tid < BN) {
    float A0 = smf[tid],       B0 = smf[128 + tid];
    float A1 = smf[64 + tid],  B1 = smf[192 + tid];
    float Af = A0 * A1;
    float Bf = fmaf(A1, B0, B1);
    int jj = h * BW + j0 + tid;
    cA[mt * WIDTH + jj] = Af;   // chunk index == mt (BM == CS)
    cB[mt * WIDTH + jj] = Bf;
  }
}

// ---- scan phase B: prefix over chunks ----
__global__ void scan_prefix(const float* __restrict__ cA, const float* __restrict__ cB,
                            float* __restrict__ prefix) {
  int c = blockIdx.x * 256 + threadIdx.x;
  float hcur = 0.f;
  for (int i0 = 0; i0 < NCHUNK; i0 += 8) {
    float av[8], bv[8];
    #pragma unroll
    for (int e = 0; e < 8; e++) { av[e] = cA[(i0 + e) * WIDTH + c]; bv[e] = cB[(i0 + e) * WIDTH + c]; }
    #pragma unroll
    for (int e = 0; e < 8; e++) { prefix[(i0 + e) * WIDTH + c] = hcur; hcur = av[e] * hcur + bv[e]; }
  }
}

// ---- scan phase C: apply (packed la|nx in, f32 out) ----
__global__ void scan_apply(const uint32_t* __restrict__ lanx,
                           const float* __restrict__ prefix,
                           float* __restrict__ out) {
  int chunk = blockIdx.x;
  int c0 = (blockIdx.y * 256 + threadIdx.x) * 4;
  size_t base = (size_t)chunk * CS * WIDTH + c0;
  float h[4];
  #pragma unroll
  for (int q = 0; q < 4; q++) h[q] = prefix[chunk * WIDTH + c0 + q];
  for (int rb = 0; rb < CS; rb += 4) {
    uint4 v[4];
    #pragma unroll
    for (int e = 0; e < 4; e++)
      v[e] = *reinterpret_cast<const uint4*>(lanx + base + (size_t)(rb + e) * WIDTH);
    #pragma unroll
    for (int e = 0; e < 4; e++) {
      float4 ov;
      h[0] = fmaf(__expf(bf16_to_f32(v[e].x & 0xffffu)), h[0], bf16_to_f32(v[e].x >> 16)); ov.x = h[0];
      h[1] = fmaf(__expf(bf16_to_f32(v[e].y & 0xffffu)), h[1], bf16_to_f32(v[e].y >> 16)); ov.y = h[1];
      h[2] = fmaf(__expf(bf16_to_f32(v[e].z & 0xffffu)), h[2], bf16_to_f32(v[e].z >> 16)); ov.z = h[2];
      h[3] = fmaf(__expf(bf16_to_f32(v[e].w & 0xffffu)), h[3], bf16_to_f32(v[e].w >> 16)); ov.w = h[3];
      *reinterpret_cast<float4*>(out + base + (size_t)(rb + e) * WIDTH) = ov;
    }
  }
}

extern "C" void kernel_launch(void* const* d_in, const int* in_sizes, int n_in,
                              void* d_out, int out_size, void* d_ws, size_t ws_size,
                              hipStream_t stream) {
  const float* x       = (const float*)d_in[0];
  const int*   s       = (const int*)d_in[1];
  const float* a_param = (const float*)d_in[2];
  const float* ig_w    = (const float*)d_in[3];
  const float* ig_b    = (const float*)d_in[4];
  const float* ag_w    = (const float*)d_in[5];
  const float* ag_b    = (const float*)d_in[6];
  float* out = (float*)d_out;
  char* ws = (char*)d_ws;

  uint32_t* lanx   = (uint32_t*)ws;                     // 134217728 B
  uint16_t* wt     = (uint16_t*)(ws + 134217728);       //   8388608 B
  float*    cvec   = (float*)(ws + 142606336);          //     16384 B
  float*    cA     = (float*)(ws + 142622720);          //   1048576 B
  float*    cB     = (float*)(ws + 143671296);          //   1048576 B
  float*    prefix = (float*)(ws + 144719872);          //   1048576 B

  prep_weights<<<dim3(16, 16, 16), 256, 0, stream>>>(ig_w, ag_w, wt);
  prep_misc<<<dim3(16), 256, 0, stream>>>(a_param, cvec);
  gates_gemm<<<dim3(4096), 256, 0, stream>>>(x, s, wt, ig_b, ag_b, cvec,
                                             lanx, cA, cB);
  scan_prefix<<<dim3(16), 256, 0, stream>>>(cA, cB, prefix);
  scan_apply<<<dim3(NCHUNK, 4), 256, 0, stream>>>(lanx, prefix, out);
}